// Round 5
// baseline (119.823 us; speedup 1.0000x reference)
//
#include <hip/hip_runtime.h>
#include <math.h>

#define HAND_PARAM_DIM 32
#define INF_DIST 1000000.0f
#define EPS 1e-8f
#define NROW 64        // B*S
#define HW_N 65536
#define NV 778
#define NMESH 1556
#define NQ 389          // mesh points per quarter (4*389 = 1556)
#define K_SEL 1024u
#define HALF_BITS  0x3F000000u  // bits of 0.5f
#define GUESS_BITS 0x3F733333u  // bits of 0.95f (speculative collect threshold)
#define CAND_CAP 4096
#define CHUNK_CAP 1024
#define FIX_SCALE 4294967296.0  // 2^32 fixed-point scale

// ---- workspace layout (bytes) ----
#define OFF_CAND 0u             // 64*4096*8  = 2097152
#define OFF_MESH 2097152u       // 64*1556*16 = 1593344
#define OFF_SAMP 3690496u       // 64*1024*16 = 1048576
#define OFF_MIN  4739072u       // 65536*4    = 262144
#define OFF_CTR  5001216u       // u32 words: [0:64) ccount, [64:128) rowbad,
                                // [128:192) rowtick, [192:194) gsum(i64), [194] gcnt, [195] done
#define CTR_WORDS 196

typedef unsigned long long u64;

// ---------------------------------------------------------------------------
// Kernel 0: init. 64 blocks: minbuf -> 0xFFFFFFFF (max key); block 0: ctr -> 0.
// ---------------------------------------------------------------------------
__global__ void __launch_bounds__(256) zero_kernel(uint4* __restrict__ minbuf4,
                                                   unsigned* __restrict__ ctr) {
    int t = threadIdx.x;
    minbuf4[blockIdx.x * 256 + t] = make_uint4(~0u, ~0u, ~0u, ~0u);
    if (blockIdx.x == 0 && t < CTR_WORDS) ctr[t] = 0u;
}

// ---------------------------------------------------------------------------
// Kernel 1: blocks 0..1023 = speculative collect (1 pass over mask);
//           blocks 1024..1151 = MANO mesh points.
// Mesh is stored pre-scaled: m.xyz = -2*p, m.w = |p|^2, so the NN metric is
// d = fma(sx,m.x, fma(sy,m.y, fma(sz,m.z, m.w))) = |p|^2 - 2 s.p
// ---------------------------------------------------------------------------
__global__ void __launch_bounds__(256) combo_kernel(
    const float* __restrict__ mask, const int* __restrict__ hv,
    u64* __restrict__ cand, unsigned* __restrict__ ccount, unsigned* __restrict__ rowbad,
    const float* __restrict__ hp,
    const float* __restrict__ vtl, const float* __restrict__ vtr,
    const float* __restrict__ sdl, const float* __restrict__ sdr,
    const float* __restrict__ pdl, const float* __restrict__ pdr,
    float4* __restrict__ meshQ)
{
    __shared__ u64 loc[CHUNK_CAP];
    __shared__ unsigned nc, base;
    int blk = blockIdx.x;
    int t = threadIdx.x;

    if (blk < 1024) {
        int row = blk >> 4, chunk = blk & 15;
        if (!(hv[row*2] | hv[row*2+1])) return;
        if (t == 0) nc = 0u;
        __syncthreads();
        const float4* m4 = (const float4*)(mask + (size_t)row * HW_N + chunk * 4096);
#pragma unroll
        for (int k = 0; k < 4; k++) {
            float4 v = m4[k*256 + t];
            unsigned e0 = (unsigned)(chunk*4096 + k*1024 + t*4);
            unsigned u;
            u = __float_as_uint(v.x);
            if (u >= GUESS_BITS) { unsigned p = atomicAdd(&nc,1u); if (p < CHUNK_CAP) loc[p] = ((u64)u<<32)|(e0+0u); }
            u = __float_as_uint(v.y);
            if (u >= GUESS_BITS) { unsigned p = atomicAdd(&nc,1u); if (p < CHUNK_CAP) loc[p] = ((u64)u<<32)|(e0+1u); }
            u = __float_as_uint(v.z);
            if (u >= GUESS_BITS) { unsigned p = atomicAdd(&nc,1u); if (p < CHUNK_CAP) loc[p] = ((u64)u<<32)|(e0+2u); }
            u = __float_as_uint(v.w);
            if (u >= GUESS_BITS) { unsigned p = atomicAdd(&nc,1u); if (p < CHUNK_CAP) loc[p] = ((u64)u<<32)|(e0+3u); }
        }
        __syncthreads();
        unsigned n = (nc < CHUNK_CAP) ? nc : CHUNK_CAP;
        if (t == 0) {
            if (nc > CHUNK_CAP) rowbad[row] = 1u;
            base = atomicAdd(&ccount[row], n);
        }
        __syncthreads();
        unsigned b = base;
        for (unsigned i = t; i < n; i += 256) {
            unsigned p = b + i;
            if (p < CAND_CAP) cand[(size_t)row * CAND_CAP + p] = loc[i];
        }
        return;
    }

    // ---- mesh points ----
    int mb   = blk - 1024;
    int row  = mb >> 1;
    int hand = mb & 1;
    const float* p = hp + row * (2 * HAND_PARAM_DIM) + hand * HAND_PARAM_DIM;
    int valid = hv[row * 2 + hand];

    const float* vt = hand ? vtr : vtl;
    const float* sd = hand ? sdr : sdl;
    const float* pd = hand ? pdr : pdl;

    float tx = p[0], ty = p[1], tz = p[2];
    float q0 = p[3], q1 = p[4], q2 = p[5], q3 = p[6];
    float qn = sqrtf(q0*q0 + q1*q1 + q2*q2 + q3*q3 + EPS);
    float inv = 1.0f / fmaxf(qn, EPS);
    q0 *= inv; q1 *= inv; q2 *= inv; q3 *= inv;
    float sgn = (q0 < 0.0f) ? -1.0f : 1.0f;
    q0 *= sgn; q1 *= sgn; q2 *= sgn; q3 *= sgn;
    float sin_half = sqrtf(q1*q1 + q2*q2 + q3*q3 + EPS);
    float w_safe = fminf(fmaxf(q0, -1.0f + EPS), 1.0f - EPS);
    float ang2 = 2.0f * atan2f(sin_half, w_safe);
    float factor = (sin_half < 1e-6f) ? 2.0f : ang2 / fmaxf(sin_half, EPS);
    float rx = q1 * factor, ry = q2 * factor, rz = q3 * factor;
    float ang = sqrtf(rx*rx + ry*ry + rz*rz + EPS);
    float iang = 1.0f / ang;
    float ax = rx * iang, ay = ry * iang, az = rz * iang;
    float c = cosf(ang), s = sinf(ang), omc = 1.0f - c;

    float pose[15], betas[10];
#pragma unroll
    for (int k = 0; k < 15; k++) pose[k] = p[7 + k];
#pragma unroll
    for (int k = 0; k < 10; k++) betas[k] = p[22 + k];

    for (int v = t; v < NV; v += 256) {
        float px = vt[v*3+0], py = vt[v*3+1], pz = vt[v*3+2];
        const float* sdv = sd + v * 30;
#pragma unroll
        for (int k = 0; k < 10; k++) {
            px = fmaf(sdv[k],      betas[k], px);
            py = fmaf(sdv[10 + k], betas[k], py);
            pz = fmaf(sdv[20 + k], betas[k], pz);
        }
        const float* pdv = pd + v * 45;
#pragma unroll
        for (int k = 0; k < 15; k++) {
            px = fmaf(pdv[k],      pose[k], px);
            py = fmaf(pdv[15 + k], pose[k], py);
            pz = fmaf(pdv[30 + k], pose[k], pz);
        }
        float cx = ay * pz - az * py;
        float cy = az * px - ax * pz;
        float cz = ax * py - ay * px;
        float kdv = ax * px + ay * py + az * pz;
        float ox = px * c + cx * s + ax * kdv * omc + tx;
        float oy = py * c + cy * s + ay * kdv * omc + ty;
        float oz = pz * c + cz * s + az * kdv * omc + tz;
        if (!valid) { ox = INF_DIST; oy = INF_DIST; oz = INF_DIST; }
        float sb = fmaf(ox, ox, fmaf(oy, oy, oz * oz));
        meshQ[row * NMESH + hand * NV + v] = make_float4(-2.0f*ox, -2.0f*oy, -2.0f*oz, sb);
    }
}

// ---------------------------------------------------------------------------
// Kernel 2: per-row exact top-1024 (radix over LDS candidates; exact global
// fallback). Emits sampbuf[row][i] = (x, y, z, val>0.5 ? |s|^2 : -1).
// Slot order is nondeterministic; all downstream reductions are order-free.
// ---------------------------------------------------------------------------
__global__ void __launch_bounds__(256) sel_fin_kernel(
    const float* __restrict__ mask, const float* __restrict__ means,
    const int* __restrict__ hv,
    const u64* __restrict__ cand, const unsigned* __restrict__ ccount,
    const unsigned* __restrict__ rowbad, float4* __restrict__ sampbuf)
{
    __shared__ unsigned cval[CAND_CAP], cidx[CAND_CAP];   // 32 KB
    __shared__ unsigned h[256], seg[256];
    __shared__ unsigned sbin, sRn;
    __shared__ unsigned tlist[256];
    __shared__ unsigned tn, ns, scut;
    int row = blockIdx.x, t = threadIdx.x;

    // prefill (invalid marker) — must happen even for invalid rows
    for (unsigned i = t; i < K_SEL; i += 256)
        sampbuf[(size_t)row * K_SEL + i] = make_float4(0.f, 0.f, 0.f, -1.0f);
    __syncthreads();
    if (!(hv[row*2] | hv[row*2+1])) return;

    unsigned cnt = ccount[row];
    bool ok = (cnt >= K_SEL) && (cnt <= CAND_CAP) && (rowbad[row] == 0u);
    const float* mrow = mask + (size_t)row * HW_N;
    unsigned M = ok ? cnt : (unsigned)HW_N;

    if (ok) {
        for (unsigned i = t; i < cnt; i += 256) {
            u64 c = cand[(size_t)row * CAND_CAP + i];
            cval[i] = (unsigned)(c >> 32); cidx[i] = (unsigned)c;
        }
    }
    if (t == 0) { tn = 0u; ns = 0u; }
    __syncthreads();

    unsigned pfx = 0u, R = K_SEL;
    for (int ph = 0; ph < 4; ph++) {
        int sh = 24 - 8 * ph;
        unsigned pm = (ph == 0) ? 0u : (0xFFFFFFFFu << (sh + 8));
        h[t] = 0u;
        __syncthreads();
        for (unsigned i = t; i < M; i += 256) {
            unsigned u = ok ? cval[i] : __float_as_uint(mrow[i]);
            if ((u & pm) == pfx) atomicAdd(&h[(u >> sh) & 0xFFu], 1u);
        }
        __syncthreads();
        seg[t] = h[t];
        __syncthreads();
        for (int off = 1; off < 256; off <<= 1) {     // inclusive suffix scan
            unsigned v = (t + off < 256) ? seg[t + off] : 0u;
            __syncthreads(); seg[t] += v; __syncthreads();
        }
        unsigned excl = (t < 255) ? seg[t + 1] : 0u;
        if (excl < R && R <= seg[t]) { sbin = (unsigned)t; sRn = R - excl; }
        __syncthreads();
        pfx |= sbin << sh;
        R = sRn;
        __syncthreads();
    }
    unsigned T = pfx;
    for (unsigned i = t; i < M; i += 256) {
        unsigned u = ok ? cval[i] : __float_as_uint(mrow[i]);
        if (u == T) {
            unsigned p = atomicAdd(&tn, 1u);
            if (p < 256u) tlist[p] = ok ? cidx[i] : i;
        }
    }
    __syncthreads();
    if (t == 0) {
        unsigned n2 = (tn < 256u) ? tn : 256u;
        for (unsigned a = 1; a < n2; a++) {
            unsigned key = tlist[a]; int b = (int)a - 1;
            while (b >= 0 && tlist[b] > key) { tlist[b+1] = tlist[b]; b--; }
            tlist[b+1] = key;
        }
        unsigned r = R;
        if (r > n2) r = n2;
        if (r < 1u) r = 1u;
        scut = (n2 > 0u) ? tlist[r - 1] : 0u;
    }
    __syncthreads();
    unsigned cut = scut;
    for (unsigned i = t; i < M; i += 256) {
        unsigned u  = ok ? cval[i] : __float_as_uint(mrow[i]);
        unsigned id = ok ? cidx[i] : i;
        if (u > T || (u == T && id <= cut)) {
            unsigned p = atomicAdd(&ns, 1u);
            if (p < K_SEL) {
                const float* gm = means + ((size_t)row * HW_N + id) * 3;
                float sx = gm[0], sy = gm[1], sz = gm[2];
                float sa = fmaf(sx, sx, fmaf(sy, sy, sz * sz));
                float w  = (u > HALF_BITS) ? sa : -1.0f;
                sampbuf[(size_t)row * K_SEL + p] = make_float4(sx, sy, sz, w);
            }
        }
    }
}

// ---------------------------------------------------------------------------
// Kernel 3: NN distance. 1024 blocks = (row, sample-chunk, mesh-quarter).
// Each lane holds 4 samples in regs; one broadcast LDS point-read serves 256
// pairs. Cross-block per-sample min via atomicMin on monotone-encoded bits.
// Per-row ticket: 16th block sums its row; global ticket: 64th writes out.
// ---------------------------------------------------------------------------
__global__ void __launch_bounds__(256) dist_kernel(
    const float4* __restrict__ meshQ, const float4* __restrict__ sampbuf,
    unsigned* __restrict__ minbuf, unsigned* __restrict__ rowtick,
    u64* __restrict__ gsum, unsigned* __restrict__ gcnt, unsigned* __restrict__ done,
    float* __restrict__ out)
{
    __shared__ float4 mq[NQ];
    __shared__ float redm[4 * 256];
    __shared__ long long rsum[256];
    __shared__ unsigned rcnt[256];
    __shared__ unsigned stick;
    int blk = blockIdx.x;
    int row = blk >> 4, sc = (blk >> 2) & 3, qt = blk & 3;
    int t = threadIdx.x;
    int l = t & 63, q = t >> 6;
    int base = row * (int)K_SEL + sc * 256;

    for (int i = t; i < NQ; i += 256) mq[i] = meshQ[row * NMESH + qt * NQ + i];

    float sx0, sy0, sz0, sx1, sy1, sz1, sx2, sy2, sz2, sx3, sy3, sz3;
    {
        float4 s0 = sampbuf[base + 0*64 + l];
        float4 s1 = sampbuf[base + 1*64 + l];
        float4 s2 = sampbuf[base + 2*64 + l];
        float4 s3 = sampbuf[base + 3*64 + l];
        sx0 = s0.x; sy0 = s0.y; sz0 = s0.z;
        sx1 = s1.x; sy1 = s1.y; sz1 = s1.z;
        sx2 = s2.x; sy2 = s2.y; sz2 = s2.z;
        sx3 = s3.x; sy3 = s3.y; sz3 = s3.z;
    }
    float mn0 = 3.4e38f, mn1 = 3.4e38f, mn2 = 3.4e38f, mn3 = 3.4e38f;
    __syncthreads();

#pragma unroll 2
    for (int i = q; i < NQ; i += 4) {
        float4 a = mq[i];
        float d0 = fmaf(sx0, a.x, fmaf(sy0, a.y, fmaf(sz0, a.z, a.w)));
        float d1 = fmaf(sx1, a.x, fmaf(sy1, a.y, fmaf(sz1, a.z, a.w)));
        float d2 = fmaf(sx2, a.x, fmaf(sy2, a.y, fmaf(sz2, a.z, a.w)));
        float d3 = fmaf(sx3, a.x, fmaf(sy3, a.y, fmaf(sz3, a.z, a.w)));
        mn0 = fminf(mn0, d0);
        mn1 = fminf(mn1, d1);
        mn2 = fminf(mn2, d2);
        mn3 = fminf(mn3, d3);
    }
    redm[q*256 + 0*64 + l] = mn0;
    redm[q*256 + 1*64 + l] = mn1;
    redm[q*256 + 2*64 + l] = mn2;
    redm[q*256 + 3*64 + l] = mn3;
    __syncthreads();
    {
        float m = fminf(fminf(redm[t], redm[256 + t]),
                        fminf(redm[512 + t], redm[768 + t]));
        float4 sp = sampbuf[base + t];
        if (sp.w >= 0.0f) {
            unsigned u = __float_as_uint(m);
            unsigned key = (u & 0x80000000u) ? ~u : (u | 0x80000000u);
            atomicMin(&minbuf[base + t], key);
        }
    }
    __syncthreads();
    __threadfence();
    if (t == 0) stick = atomicAdd(&rowtick[row], 1u);
    __syncthreads();
    if (stick != 15u) return;

    // ---- row finisher: all 16 blocks of this row are done ----
    long long accl = 0; unsigned accc = 0;
    for (int i = t; i < (int)K_SEL; i += 256) {
        float4 sp = sampbuf[row * (int)K_SEL + i];
        if (sp.w >= 0.0f) {
            unsigned key = atomicMin(&minbuf[row * (int)K_SEL + i], 0xFFFFFFFFu); // atomic read
            unsigned u = (key & 0x80000000u) ? (key ^ 0x80000000u) : ~key;
            float mval = __uint_as_float(u);
            float d2 = fmaxf(mval + sp.w, 0.0f);
            accl += (long long)((double)d2 * FIX_SCALE);
            accc += 1u;
        }
    }
    rsum[t] = accl; rcnt[t] = accc;
    __syncthreads();
    for (int off = 128; off > 0; off >>= 1) {
        if (t < off) { rsum[t] += rsum[t+off]; rcnt[t] += rcnt[t+off]; }
        __syncthreads();
    }
    if (t == 0) {
        atomicAdd(gsum, (u64)rsum[0]);
        atomicAdd(gcnt, rcnt[0]);
        __threadfence();
        unsigned dk = atomicAdd(done, 1u);
        if (dk == (unsigned)(NROW - 1)) {
            u64 sbits = atomicAdd(gsum, 0ull);
            unsigned cc = atomicAdd(gcnt, 0u);
            double sum = (double)(long long)sbits / FIX_SCALE;
            out[0] = (float)(sum / (double)(cc ? cc : 1u));
        }
    }
}

extern "C" void kernel_launch(void* const* d_in, const int* in_sizes, int n_in,
                              void* d_out, int out_size, void* d_ws, size_t ws_size,
                              hipStream_t stream) {
    const float* hp    = (const float*)d_in[0];
    const float* means = (const float*)d_in[1];
    const float* mask  = (const float*)d_in[2];
    const int*   hv    = (const int*)  d_in[3];
    const float* vtl   = (const float*)d_in[4];
    const float* vtr   = (const float*)d_in[5];
    const float* sdl   = (const float*)d_in[6];
    const float* sdr   = (const float*)d_in[7];
    const float* pdl   = (const float*)d_in[8];
    const float* pdr   = (const float*)d_in[9];
    float* out = (float*)d_out;

    char* ws = (char*)d_ws;
    u64*      cand    = (u64*)(ws + OFF_CAND);
    float4*   meshQ   = (float4*)(ws + OFF_MESH);
    float4*   sampbuf = (float4*)(ws + OFF_SAMP);
    unsigned* minbuf  = (unsigned*)(ws + OFF_MIN);
    unsigned* ctr     = (unsigned*)(ws + OFF_CTR);
    unsigned* ccount  = ctr;            // [0:64)
    unsigned* rowbad  = ctr + 64;       // [64:128)
    unsigned* rowtick = ctr + 128;      // [128:192)
    u64*      gsum    = (u64*)(ctr + 192);
    unsigned* gcnt    = ctr + 194;
    unsigned* done    = ctr + 195;

    zero_kernel<<<NROW, 256, 0, stream>>>((uint4*)minbuf, ctr);
    combo_kernel<<<1024 + 128, 256, 0, stream>>>(mask, hv, cand, ccount, rowbad,
                                                 hp, vtl, vtr, sdl, sdr, pdl, pdr, meshQ);
    sel_fin_kernel<<<NROW, 256, 0, stream>>>(mask, means, hv, cand, ccount, rowbad, sampbuf);
    dist_kernel<<<NROW * 16, 256, 0, stream>>>(meshQ, sampbuf, minbuf, rowtick,
                                               gsum, gcnt, done, out);
}

// Round 6
// 71.239 us; speedup vs baseline: 1.6820x; 1.6820x over previous
//
#include <hip/hip_runtime.h>
#include <math.h>

#define HAND_PARAM_DIM 32
#define INF_DIST 1000000.0f
#define EPS 1e-8f
#define NROW 64        // B*S
#define HW_N 65536
#define NV 778
#define NMESH 1556
#define NMESH_PAD 1568  // 16 slices * 98
#define SLICE 98
#define NSLICE 16
#define K_SEL 1024u
#define HALF_BITS  0x3F000000u  // bits of 0.5f
#define GUESS_BITS 0x3F733333u  // bits of 0.95f (speculative collect threshold)
#define CAND_CAP 4096
#define CHUNK_CAP 1024
#define FIX_SCALE 4294967296.0  // 2^32 fixed-point scale

// ---- workspace layout (bytes) ----
#define OFF_CAND 0u             // 64*4096*8  = 2097152
#define OFF_MESH 2097152u       // 64*1568*16 = 1605632
#define OFF_SAMP 3702784u       // 64*1024*16 = 1048576
#define OFF_MINP 4751360u       // 64*16*1024*4 = 4194304
#define OFF_PART 8945664u       // 256*8 (i64)
#define OFF_PCNT 8947712u       // 256*4
#define OFF_CTR  8948736u       // u32: [0:64) ccount, [64:128) rowbad
#define CTR_WORDS 128

typedef unsigned long long u64;

// ---------------------------------------------------------------------------
// Kernel 0: zero per-launch counters.
// ---------------------------------------------------------------------------
__global__ void __launch_bounds__(128) zero_kernel(unsigned* __restrict__ ctr) {
    ctr[threadIdx.x] = 0u;
}

// ---------------------------------------------------------------------------
// Kernel 1: blocks 0..1023 = speculative collect (1 pass over mask);
//           blocks 1024..1151 = MANO mesh points.
// Mesh stored pre-scaled: m.xyz = -2*p, m.w = |p|^2, so NN metric is
// d = fma(sx,m.x, fma(sy,m.y, fma(sz,m.z, m.w))) = |p|^2 - 2 s.p
// Rows are padded to 1568 points with w=+3.4e38 sentinels.
// ---------------------------------------------------------------------------
__global__ void __launch_bounds__(256) combo_kernel(
    const float* __restrict__ mask, const int* __restrict__ hv,
    u64* __restrict__ cand, unsigned* __restrict__ ccount, unsigned* __restrict__ rowbad,
    const float* __restrict__ hp,
    const float* __restrict__ vtl, const float* __restrict__ vtr,
    const float* __restrict__ sdl, const float* __restrict__ sdr,
    const float* __restrict__ pdl, const float* __restrict__ pdr,
    float4* __restrict__ meshP)
{
    __shared__ u64 loc[CHUNK_CAP];
    __shared__ unsigned nc, base;
    int blk = blockIdx.x;
    int t = threadIdx.x;

    if (blk < 1024) {
        int row = blk >> 4, chunk = blk & 15;
        if (!(hv[row*2] | hv[row*2+1])) return;
        if (t == 0) nc = 0u;
        __syncthreads();
        const float4* m4 = (const float4*)(mask + (size_t)row * HW_N + chunk * 4096);
#pragma unroll
        for (int k = 0; k < 4; k++) {
            float4 v = m4[k*256 + t];
            unsigned e0 = (unsigned)(chunk*4096 + k*1024 + t*4);
            unsigned u;
            u = __float_as_uint(v.x);
            if (u >= GUESS_BITS) { unsigned p = atomicAdd(&nc,1u); if (p < CHUNK_CAP) loc[p] = ((u64)u<<32)|(e0+0u); }
            u = __float_as_uint(v.y);
            if (u >= GUESS_BITS) { unsigned p = atomicAdd(&nc,1u); if (p < CHUNK_CAP) loc[p] = ((u64)u<<32)|(e0+1u); }
            u = __float_as_uint(v.z);
            if (u >= GUESS_BITS) { unsigned p = atomicAdd(&nc,1u); if (p < CHUNK_CAP) loc[p] = ((u64)u<<32)|(e0+2u); }
            u = __float_as_uint(v.w);
            if (u >= GUESS_BITS) { unsigned p = atomicAdd(&nc,1u); if (p < CHUNK_CAP) loc[p] = ((u64)u<<32)|(e0+3u); }
        }
        __syncthreads();
        unsigned n = (nc < CHUNK_CAP) ? nc : CHUNK_CAP;
        if (t == 0) {
            if (nc > CHUNK_CAP) rowbad[row] = 1u;
            base = atomicAdd(&ccount[row], n);
        }
        __syncthreads();
        unsigned b = base;
        for (unsigned i = t; i < n; i += 256) {
            unsigned p = b + i;
            if (p < CAND_CAP) cand[(size_t)row * CAND_CAP + p] = loc[i];
        }
        return;
    }

    // ---- mesh points ----
    int mb   = blk - 1024;
    int row  = mb >> 1;
    int hand = mb & 1;
    const float* p = hp + row * (2 * HAND_PARAM_DIM) + hand * HAND_PARAM_DIM;
    int valid = hv[row * 2 + hand];

    const float* vt = hand ? vtr : vtl;
    const float* sd = hand ? sdr : sdl;
    const float* pd = hand ? pdr : pdl;

    // pad sentinels (hand==1 block owns them)
    if (hand == 1 && t < (NMESH_PAD - NMESH))
        meshP[row * NMESH_PAD + NMESH + t] = make_float4(0.f, 0.f, 0.f, 3.4e38f);

    float tx = p[0], ty = p[1], tz = p[2];
    float q0 = p[3], q1 = p[4], q2 = p[5], q3 = p[6];
    float qn = sqrtf(q0*q0 + q1*q1 + q2*q2 + q3*q3 + EPS);
    float inv = 1.0f / fmaxf(qn, EPS);
    q0 *= inv; q1 *= inv; q2 *= inv; q3 *= inv;
    float sgn = (q0 < 0.0f) ? -1.0f : 1.0f;
    q0 *= sgn; q1 *= sgn; q2 *= sgn; q3 *= sgn;
    float sin_half = sqrtf(q1*q1 + q2*q2 + q3*q3 + EPS);
    float w_safe = fminf(fmaxf(q0, -1.0f + EPS), 1.0f - EPS);
    float ang2 = 2.0f * atan2f(sin_half, w_safe);
    float factor = (sin_half < 1e-6f) ? 2.0f : ang2 / fmaxf(sin_half, EPS);
    float rx = q1 * factor, ry = q2 * factor, rz = q3 * factor;
    float ang = sqrtf(rx*rx + ry*ry + rz*rz + EPS);
    float iang = 1.0f / ang;
    float ax = rx * iang, ay = ry * iang, az = rz * iang;
    float c = cosf(ang), s = sinf(ang), omc = 1.0f - c;

    float pose[15], betas[10];
#pragma unroll
    for (int k = 0; k < 15; k++) pose[k] = p[7 + k];
#pragma unroll
    for (int k = 0; k < 10; k++) betas[k] = p[22 + k];

    for (int v = t; v < NV; v += 256) {
        float px = vt[v*3+0], py = vt[v*3+1], pz = vt[v*3+2];
        const float* sdv = sd + v * 30;
#pragma unroll
        for (int k = 0; k < 10; k++) {
            px = fmaf(sdv[k],      betas[k], px);
            py = fmaf(sdv[10 + k], betas[k], py);
            pz = fmaf(sdv[20 + k], betas[k], pz);
        }
        const float* pdv = pd + v * 45;
#pragma unroll
        for (int k = 0; k < 15; k++) {
            px = fmaf(pdv[k],      pose[k], px);
            py = fmaf(pdv[15 + k], pose[k], py);
            pz = fmaf(pdv[30 + k], pose[k], pz);
        }
        float cx = ay * pz - az * py;
        float cy = az * px - ax * pz;
        float cz = ax * py - ay * px;
        float kdv = ax * px + ay * py + az * pz;
        float ox = px * c + cx * s + ax * kdv * omc + tx;
        float oy = py * c + cy * s + ay * kdv * omc + ty;
        float oz = pz * c + cz * s + az * kdv * omc + tz;
        if (!valid) { ox = INF_DIST; oy = INF_DIST; oz = INF_DIST; }
        float sb = fmaf(ox, ox, fmaf(oy, oy, oz * oz));
        meshP[row * NMESH_PAD + hand * NV + v] = make_float4(-2.0f*ox, -2.0f*oy, -2.0f*oz, sb);
    }
}

// ---------------------------------------------------------------------------
// Kernel 2: per-row exact top-1024 (radix over LDS candidates; exact global
// fallback). Emits sampbuf[row][i] = (x, y, z, val>0.5 ? |s|^2 : -1).
// Slot order is nondeterministic; all downstream reductions are order-free.
// ---------------------------------------------------------------------------
__global__ void __launch_bounds__(256) sel_fin_kernel(
    const float* __restrict__ mask, const float* __restrict__ means,
    const int* __restrict__ hv,
    const u64* __restrict__ cand, const unsigned* __restrict__ ccount,
    const unsigned* __restrict__ rowbad, float4* __restrict__ sampbuf)
{
    __shared__ unsigned cval[CAND_CAP], cidx[CAND_CAP];   // 32 KB
    __shared__ unsigned h[256], seg[256];
    __shared__ unsigned sbin, sRn;
    __shared__ unsigned tlist[256];
    __shared__ unsigned tn, ns, scut;
    int row = blockIdx.x, t = threadIdx.x;

    for (unsigned i = t; i < K_SEL; i += 256)
        sampbuf[(size_t)row * K_SEL + i] = make_float4(0.f, 0.f, 0.f, -1.0f);
    __syncthreads();
    if (!(hv[row*2] | hv[row*2+1])) return;

    unsigned cnt = ccount[row];
    bool ok = (cnt >= K_SEL) && (cnt <= CAND_CAP) && (rowbad[row] == 0u);
    const float* mrow = mask + (size_t)row * HW_N;
    unsigned M = ok ? cnt : (unsigned)HW_N;

    if (ok) {
        for (unsigned i = t; i < cnt; i += 256) {
            u64 c = cand[(size_t)row * CAND_CAP + i];
            cval[i] = (unsigned)(c >> 32); cidx[i] = (unsigned)c;
        }
    }
    if (t == 0) { tn = 0u; ns = 0u; }
    __syncthreads();

    unsigned pfx = 0u, R = K_SEL;
    for (int ph = 0; ph < 4; ph++) {
        int sh = 24 - 8 * ph;
        unsigned pm = (ph == 0) ? 0u : (0xFFFFFFFFu << (sh + 8));
        h[t] = 0u;
        __syncthreads();
        for (unsigned i = t; i < M; i += 256) {
            unsigned u = ok ? cval[i] : __float_as_uint(mrow[i]);
            if ((u & pm) == pfx) atomicAdd(&h[(u >> sh) & 0xFFu], 1u);
        }
        __syncthreads();
        seg[t] = h[t];
        __syncthreads();
        for (int off = 1; off < 256; off <<= 1) {     // inclusive suffix scan
            unsigned v = (t + off < 256) ? seg[t + off] : 0u;
            __syncthreads(); seg[t] += v; __syncthreads();
        }
        unsigned excl = (t < 255) ? seg[t + 1] : 0u;
        if (excl < R && R <= seg[t]) { sbin = (unsigned)t; sRn = R - excl; }
        __syncthreads();
        pfx |= sbin << sh;
        R = sRn;
        __syncthreads();
    }
    unsigned T = pfx;
    for (unsigned i = t; i < M; i += 256) {
        unsigned u = ok ? cval[i] : __float_as_uint(mrow[i]);
        if (u == T) {
            unsigned p = atomicAdd(&tn, 1u);
            if (p < 256u) tlist[p] = ok ? cidx[i] : i;
        }
    }
    __syncthreads();
    if (t == 0) {
        unsigned n2 = (tn < 256u) ? tn : 256u;
        for (unsigned a = 1; a < n2; a++) {
            unsigned key = tlist[a]; int b = (int)a - 1;
            while (b >= 0 && tlist[b] > key) { tlist[b+1] = tlist[b]; b--; }
            tlist[b+1] = key;
        }
        unsigned r = R;
        if (r > n2) r = n2;
        if (r < 1u) r = 1u;
        scut = (n2 > 0u) ? tlist[r - 1] : 0u;
    }
    __syncthreads();
    unsigned cut = scut;
    for (unsigned i = t; i < M; i += 256) {
        unsigned u  = ok ? cval[i] : __float_as_uint(mrow[i]);
        unsigned id = ok ? cidx[i] : i;
        if (u > T || (u == T && id <= cut)) {
            unsigned p = atomicAdd(&ns, 1u);
            if (p < K_SEL) {
                const float* gm = means + ((size_t)row * HW_N + id) * 3;
                float sx = gm[0], sy = gm[1], sz = gm[2];
                float sa = fmaf(sx, sx, fmaf(sy, sy, sz * sz));
                float w  = (u > HALF_BITS) ? sa : -1.0f;
                sampbuf[(size_t)row * K_SEL + p] = make_float4(sx, sy, sz, w);
            }
        }
    }
}

// ---------------------------------------------------------------------------
// Kernel 3: NN partial mins. 1024 blocks = (row, mesh-slice of 98 points).
// 128 threads; each lane holds 8 samples in regs -> one broadcast LDS read
// serves 512 pairs. No atomics, no fences: block writes its own minpart slice.
// ---------------------------------------------------------------------------
__global__ void __launch_bounds__(128) dist_kernel(
    const float4* __restrict__ meshP, const float4* __restrict__ sampbuf,
    float* __restrict__ minpart)
{
    __shared__ float4 mq[SLICE];
    int blk = blockIdx.x;
    int r = blk >> 4, sl = blk & 15;
    int t = threadIdx.x;

    if (t < SLICE) mq[t] = meshP[r * NMESH_PAD + sl * SLICE + t];

    const float4* sb = sampbuf + (size_t)r * K_SEL;
    float sx[8], sy[8], sz[8], mn[8];
#pragma unroll
    for (int k = 0; k < 8; k++) {
        float4 s = sb[t + 128*k];
        sx[k] = s.x; sy[k] = s.y; sz[k] = s.z;
        mn[k] = 3.4e38f;
    }
    __syncthreads();

#pragma unroll 2
    for (int i = 0; i < SLICE; i++) {
        float4 a = mq[i];
#pragma unroll
        for (int k = 0; k < 8; k++)
            mn[k] = fminf(mn[k], fmaf(sx[k], a.x, fmaf(sy[k], a.y, fmaf(sz[k], a.z, a.w))));
    }

    float* mp = minpart + ((size_t)r * NSLICE + sl) * K_SEL;
#pragma unroll
    for (int k = 0; k < 8; k++) mp[t + 128*k] = mn[k];
}

// ---------------------------------------------------------------------------
// Kernel 4: per-sample min over 16 slices + fixed-point block partial.
// 256 blocks = (row, quarter). No atomics.
// ---------------------------------------------------------------------------
__global__ void __launch_bounds__(256) reduce_kernel(
    const float* __restrict__ minpart, const float4* __restrict__ sampbuf,
    long long* __restrict__ partial, unsigned* __restrict__ pcnt)
{
    __shared__ long long rs[256];
    __shared__ unsigned rc[256];
    int blk = blockIdx.x;
    int r = blk >> 2, q = blk & 3;
    int t = threadIdx.x;
    int j = q * 256 + t;

    const float* mp = minpart + (size_t)r * NSLICE * K_SEL + j;
    float m = mp[0];
#pragma unroll
    for (int s = 1; s < NSLICE; s++) m = fminf(m, mp[s * (int)K_SEL]);

    float4 sp = sampbuf[(size_t)r * K_SEL + j];
    long long acc = 0; unsigned c = 0;
    if (sp.w >= 0.0f) {
        float d2 = fmaxf(m + sp.w, 0.0f);
        acc = (long long)((double)d2 * FIX_SCALE);
        c = 1u;
    }
    rs[t] = acc; rc[t] = c;
    __syncthreads();
    for (int off = 128; off > 0; off >>= 1) {
        if (t < off) { rs[t] += rs[t+off]; rc[t] += rc[t+off]; }
        __syncthreads();
    }
    if (t == 0) { partial[blk] = rs[0]; pcnt[blk] = rc[0]; }
}

// ---------------------------------------------------------------------------
// Kernel 5: final deterministic reduce (integer -> order-invariant).
// ---------------------------------------------------------------------------
__global__ void __launch_bounds__(256) finish_kernel(
    const long long* __restrict__ partial, const unsigned* __restrict__ pcnt,
    float* __restrict__ out)
{
    __shared__ long long rs[256];
    __shared__ unsigned rc[256];
    int t = threadIdx.x;
    rs[t] = partial[t]; rc[t] = pcnt[t];
    __syncthreads();
    for (int off = 128; off > 0; off >>= 1) {
        if (t < off) { rs[t] += rs[t+off]; rc[t] += rc[t+off]; }
        __syncthreads();
    }
    if (t == 0) {
        double sum = (double)rs[0] / FIX_SCALE;
        unsigned n = rc[0] ? rc[0] : 1u;
        out[0] = (float)(sum / (double)n);
    }
}

extern "C" void kernel_launch(void* const* d_in, const int* in_sizes, int n_in,
                              void* d_out, int out_size, void* d_ws, size_t ws_size,
                              hipStream_t stream) {
    const float* hp    = (const float*)d_in[0];
    const float* means = (const float*)d_in[1];
    const float* mask  = (const float*)d_in[2];
    const int*   hv    = (const int*)  d_in[3];
    const float* vtl   = (const float*)d_in[4];
    const float* vtr   = (const float*)d_in[5];
    const float* sdl   = (const float*)d_in[6];
    const float* sdr   = (const float*)d_in[7];
    const float* pdl   = (const float*)d_in[8];
    const float* pdr   = (const float*)d_in[9];
    float* out = (float*)d_out;

    char* ws = (char*)d_ws;
    u64*       cand    = (u64*)(ws + OFF_CAND);
    float4*    meshP   = (float4*)(ws + OFF_MESH);
    float4*    sampbuf = (float4*)(ws + OFF_SAMP);
    float*     minpart = (float*)(ws + OFF_MINP);
    long long* partial = (long long*)(ws + OFF_PART);
    unsigned*  pcnt    = (unsigned*)(ws + OFF_PCNT);
    unsigned*  ctr     = (unsigned*)(ws + OFF_CTR);
    unsigned*  ccount  = ctr;            // [0:64)
    unsigned*  rowbad  = ctr + 64;       // [64:128)

    zero_kernel<<<1, 128, 0, stream>>>(ctr);
    combo_kernel<<<1024 + 128, 256, 0, stream>>>(mask, hv, cand, ccount, rowbad,
                                                 hp, vtl, vtr, sdl, sdr, pdl, pdr, meshP);
    sel_fin_kernel<<<NROW, 256, 0, stream>>>(mask, means, hv, cand, ccount, rowbad, sampbuf);
    dist_kernel<<<NROW * NSLICE, 128, 0, stream>>>(meshP, sampbuf, minpart);
    reduce_kernel<<<NROW * 4, 256, 0, stream>>>(minpart, sampbuf, partial, pcnt);
    finish_kernel<<<1, 256, 0, stream>>>(partial, pcnt, out);
}

// Round 7
// 57.008 us; speedup vs baseline: 2.1019x; 1.2496x over previous
//
#include <hip/hip_runtime.h>
#include <math.h>

#define HAND_PARAM_DIM 32
#define INF_DIST 1000000.0f
#define EPS 1e-8f
#define NROW 64        // B*S
#define HW_N 65536
#define NV 778
#define NMESH 1556
#define NMESH_PAD 1568  // 16 slices * 98
#define SLICE 98
#define NSLICE 16
#define K_SEL 1024u
#define HALF_BITS  0x3F000000u  // bits of 0.5f
#define GUESS_BITS 0x3F733333u  // bits of 0.95f (speculative collect threshold)
#define TOP_BITS   0x3F800000u  // bits of 1.0f
#define CHUNK_SLOT 512          // per-(row,chunk) candidate capacity (22 sigma)
#define CAND_MAX   8192         // 16 * CHUNK_SLOT
#define FIX_SCALE 4294967296.0  // 2^32 fixed-point scale

// ---- workspace layout (bytes) ----
#define OFF_CAND 0u             // 64*16*512*8 = 4194304
#define OFF_CCNT 4194304u       // 64*16*4     = 4096
#define OFF_CTR  4198400u       // 4 u32: gsum(2), gcnt, done   (8-aligned)
#define OFF_MESH 4198416u       // 64*1568*16  = 1605632  (16-aligned)
#define OFF_SAMP 5804048u       // 64*1024*16  = 1048576
#define OFF_MINP 6852624u       // 64*16*1024*4 = 4194304

typedef unsigned long long u64;

// ---------------------------------------------------------------------------
// Kernel 1: blocks 0..1023 = speculative collect (one mask pass, NO global
// atomics: each (row,chunk) block owns cand slot range + count word);
// blocks 1024..1151 = MANO mesh points.
// Mesh stored pre-scaled: m.xyz = -2*p, m.w = |p|^2; NN metric is
// d = fma(sx,m.x, fma(sy,m.y, fma(sz,m.z, m.w))) = |p|^2 - 2 s.p
// ---------------------------------------------------------------------------
__global__ void __launch_bounds__(256) combo_kernel(
    const float* __restrict__ mask, const int* __restrict__ hv,
    u64* __restrict__ cand, unsigned* __restrict__ ccnt,
    const float* __restrict__ hp,
    const float* __restrict__ vtl, const float* __restrict__ vtr,
    const float* __restrict__ sdl, const float* __restrict__ sdr,
    const float* __restrict__ pdl, const float* __restrict__ pdr,
    float4* __restrict__ meshP)
{
    int blk = blockIdx.x;
    int t = threadIdx.x;

    if (blk < 1024) {
        __shared__ u64 loc[CHUNK_SLOT];
        __shared__ unsigned nc, nbad;
        int row = blk >> 4, chunk = blk & 15;
        if (!(hv[row*2] | hv[row*2+1])) return;   // ccnt never read for invalid rows
        if (t == 0) { nc = 0u; nbad = 0u; }
        __syncthreads();
        const float4* m4 = (const float4*)(mask + (size_t)row * HW_N + chunk * 4096);
#pragma unroll
        for (int k = 0; k < 4; k++) {
            float4 v = m4[k*256 + t];
            unsigned e0 = (unsigned)(chunk*4096 + k*1024 + t*4);
            unsigned u;
            u = __float_as_uint(v.x);
            if (u >= GUESS_BITS) { unsigned p = atomicAdd(&nc,1u); if (p < CHUNK_SLOT) loc[p] = ((u64)u<<32)|(e0+0u); if (u >= TOP_BITS) nbad = 1u; }
            u = __float_as_uint(v.y);
            if (u >= GUESS_BITS) { unsigned p = atomicAdd(&nc,1u); if (p < CHUNK_SLOT) loc[p] = ((u64)u<<32)|(e0+1u); if (u >= TOP_BITS) nbad = 1u; }
            u = __float_as_uint(v.z);
            if (u >= GUESS_BITS) { unsigned p = atomicAdd(&nc,1u); if (p < CHUNK_SLOT) loc[p] = ((u64)u<<32)|(e0+2u); if (u >= TOP_BITS) nbad = 1u; }
            u = __float_as_uint(v.w);
            if (u >= GUESS_BITS) { unsigned p = atomicAdd(&nc,1u); if (p < CHUNK_SLOT) loc[p] = ((u64)u<<32)|(e0+3u); if (u >= TOP_BITS) nbad = 1u; }
        }
        __syncthreads();
        unsigned n = (nc < CHUNK_SLOT) ? nc : CHUNK_SLOT;
        if (t == 0) ccnt[row*16 + chunk] = nc | (nbad << 31);
        u64* dst = cand + ((size_t)(row*16 + chunk)) * CHUNK_SLOT;
        for (unsigned i = t; i < n; i += 256) dst[i] = loc[i];
        return;
    }

    // ---- mesh points ----
    int mb   = blk - 1024;
    int row  = mb >> 1;
    int hand = mb & 1;
    const float* p = hp + row * (2 * HAND_PARAM_DIM) + hand * HAND_PARAM_DIM;
    int valid = hv[row * 2 + hand];

    const float* vt = hand ? vtr : vtl;
    const float* sd = hand ? sdr : sdl;
    const float* pd = hand ? pdr : pdl;

    if (hand == 1 && t < (NMESH_PAD - NMESH))
        meshP[row * NMESH_PAD + NMESH + t] = make_float4(0.f, 0.f, 0.f, 3.4e38f);

    float tx = p[0], ty = p[1], tz = p[2];
    float q0 = p[3], q1 = p[4], q2 = p[5], q3 = p[6];
    float qn = sqrtf(q0*q0 + q1*q1 + q2*q2 + q3*q3 + EPS);
    float inv = 1.0f / fmaxf(qn, EPS);
    q0 *= inv; q1 *= inv; q2 *= inv; q3 *= inv;
    float sgn = (q0 < 0.0f) ? -1.0f : 1.0f;
    q0 *= sgn; q1 *= sgn; q2 *= sgn; q3 *= sgn;
    float sin_half = sqrtf(q1*q1 + q2*q2 + q3*q3 + EPS);
    float w_safe = fminf(fmaxf(q0, -1.0f + EPS), 1.0f - EPS);
    float ang2 = 2.0f * atan2f(sin_half, w_safe);
    float factor = (sin_half < 1e-6f) ? 2.0f : ang2 / fmaxf(sin_half, EPS);
    float rx = q1 * factor, ry = q2 * factor, rz = q3 * factor;
    float ang = sqrtf(rx*rx + ry*ry + rz*rz + EPS);
    float iang = 1.0f / ang;
    float ax = rx * iang, ay = ry * iang, az = rz * iang;
    float c = cosf(ang), s = sinf(ang), omc = 1.0f - c;

    float pose[15], betas[10];
#pragma unroll
    for (int k = 0; k < 15; k++) pose[k] = p[7 + k];
#pragma unroll
    for (int k = 0; k < 10; k++) betas[k] = p[22 + k];

    for (int v = t; v < NV; v += 256) {
        float px = vt[v*3+0], py = vt[v*3+1], pz = vt[v*3+2];
        const float* sdv = sd + v * 30;
#pragma unroll
        for (int k = 0; k < 10; k++) {
            px = fmaf(sdv[k],      betas[k], px);
            py = fmaf(sdv[10 + k], betas[k], py);
            pz = fmaf(sdv[20 + k], betas[k], pz);
        }
        const float* pdv = pd + v * 45;
#pragma unroll
        for (int k = 0; k < 15; k++) {
            px = fmaf(pdv[k],      pose[k], px);
            py = fmaf(pdv[15 + k], pose[k], py);
            pz = fmaf(pdv[30 + k], pose[k], pz);
        }
        float cx = ay * pz - az * py;
        float cy = az * px - ax * pz;
        float cz = ax * py - ay * px;
        float kdv = ax * px + ay * py + az * pz;
        float ox = px * c + cx * s + ax * kdv * omc + tx;
        float oy = py * c + cy * s + ay * kdv * omc + ty;
        float oz = pz * c + cz * s + az * kdv * omc + tz;
        if (!valid) { ox = INF_DIST; oy = INF_DIST; oz = INF_DIST; }
        float sb = fmaf(ox, ox, fmaf(oy, oy, oz * oz));
        meshP[row * NMESH_PAD + hand * NV + v] = make_float4(-2.0f*ox, -2.0f*oy, -2.0f*oz, sb);
    }
}

// ---------------------------------------------------------------------------
// Kernel 2: per-row exact top-1024. Fast path: 2-phase radix on
// (bits - GUESS_BITS) (16-bit range) over the LDS candidate set. Generic
// 4-phase global fallback for anomalies. Emits
// sampbuf[row][i] = (x, y, z, val>0.5 ? |s|^2 : -1); block 0 zeroes ctr.
// ---------------------------------------------------------------------------
__global__ void __launch_bounds__(256) sel_fin_kernel(
    const float* __restrict__ mask, const float* __restrict__ means,
    const int* __restrict__ hv,
    const u64* __restrict__ cand, const unsigned* __restrict__ ccnt,
    float4* __restrict__ sampbuf, unsigned* __restrict__ ctr)
{
    __shared__ unsigned cval[CAND_MAX], cidx[CAND_MAX];   // 64 KB
    __shared__ unsigned h[256], seg[256];
    __shared__ unsigned csub[16], cbase[16];
    __shared__ unsigned sbin, sRn, sbad, stot;
    __shared__ unsigned tlist[256];
    __shared__ unsigned tn, ns, scut;
    int row = blockIdx.x, t = threadIdx.x;

    if (row == 0 && t < 4) ctr[t] = 0u;          // gsum lo/hi, gcnt, done
    for (unsigned i = t; i < K_SEL; i += 256)
        sampbuf[(size_t)row * K_SEL + i] = make_float4(0.f, 0.f, 0.f, -1.0f);
    if (!(hv[row*2] | hv[row*2+1])) return;

    if (t == 0) { sbad = 0u; tn = 0u; ns = 0u; }
    __syncthreads();
    if (t < 16) {
        unsigned w = ccnt[row*16 + t];
        unsigned n = w & 0x7FFFFFFFu;
        csub[t] = (n < CHUNK_SLOT) ? n : CHUNK_SLOT;
        if ((w >> 31) || n > CHUNK_SLOT) atomicOr(&sbad, 1u);
    }
    __syncthreads();
    if (t == 0) {
        unsigned run = 0;
#pragma unroll
        for (int c = 0; c < 16; c++) { cbase[c] = run; run += csub[c]; }
        stot = run;
    }
    __syncthreads();
    unsigned cnt = stot;
    bool ok = (sbad == 0u) && (cnt >= K_SEL) && (cnt <= CAND_MAX);
    const float* mrow = mask + (size_t)row * HW_N;
    unsigned M = ok ? cnt : (unsigned)HW_N;

    if (ok) {
#pragma unroll
        for (int c = 0; c < 16; c++) {
            unsigned n = csub[c], b = cbase[c];
            const u64* src = cand + ((size_t)(row*16 + c)) * CHUNK_SLOT;
            for (unsigned i = t; i < n; i += 256) {
                u64 e = src[i];
                cval[b + i] = (unsigned)(e >> 32); cidx[b + i] = (unsigned)e;
            }
        }
    }
    __syncthreads();

    unsigned T, R;
    if (ok) {
        // ---- 2-phase radix on 16-bit offset ----
        unsigned pfx = 0u; R = K_SEL;
        for (int ph = 0; ph < 2; ph++) {
            int sh = 8 * (1 - ph);
            h[t] = 0u;
            __syncthreads();
            for (unsigned i = t; i < cnt; i += 256) {
                unsigned off = cval[i] - GUESS_BITS;
                if (ph == 0 || (off >> 8) == pfx) atomicAdd(&h[(off >> sh) & 0xFFu], 1u);
            }
            __syncthreads();
            seg[t] = h[t];
            __syncthreads();
            for (int off2 = 1; off2 < 256; off2 <<= 1) {   // inclusive suffix scan
                unsigned v = (t + off2 < 256) ? seg[t + off2] : 0u;
                __syncthreads(); seg[t] += v; __syncthreads();
            }
            unsigned excl = (t < 255) ? seg[t + 1] : 0u;
            if (excl < R && R <= seg[t]) { sbin = (unsigned)t; sRn = R - excl; }
            __syncthreads();
            pfx = (ph == 0) ? sbin : ((pfx << 8) | sbin);
            R = sRn;
            __syncthreads();
        }
        T = GUESS_BITS + pfx;
    } else {
        // ---- generic 4-phase radix over the whole global row ----
        unsigned pfx = 0u; R = K_SEL;
        for (int ph = 0; ph < 4; ph++) {
            int sh = 24 - 8 * ph;
            unsigned pm = (ph == 0) ? 0u : (0xFFFFFFFFu << (sh + 8));
            h[t] = 0u;
            __syncthreads();
            for (unsigned i = t; i < M; i += 256) {
                unsigned u = __float_as_uint(mrow[i]);
                if ((u & pm) == pfx) atomicAdd(&h[(u >> sh) & 0xFFu], 1u);
            }
            __syncthreads();
            seg[t] = h[t];
            __syncthreads();
            for (int off2 = 1; off2 < 256; off2 <<= 1) {
                unsigned v = (t + off2 < 256) ? seg[t + off2] : 0u;
                __syncthreads(); seg[t] += v; __syncthreads();
            }
            unsigned excl = (t < 255) ? seg[t + 1] : 0u;
            if (excl < R && R <= seg[t]) { sbin = (unsigned)t; sRn = R - excl; }
            __syncthreads();
            pfx |= sbin << sh;
            R = sRn;
            __syncthreads();
        }
        T = pfx;
    }

    // ---- ties at exact value T -> R-th smallest index is the cut ----
    for (unsigned i = t; i < M; i += 256) {
        unsigned u = ok ? cval[i] : __float_as_uint(mrow[i]);
        if (u == T) {
            unsigned p = atomicAdd(&tn, 1u);
            if (p < 256u) tlist[p] = ok ? cidx[i] : i;
        }
    }
    __syncthreads();
    if (t == 0) {
        unsigned n2 = (tn < 256u) ? tn : 256u;
        for (unsigned a = 1; a < n2; a++) {
            unsigned key = tlist[a]; int b = (int)a - 1;
            while (b >= 0 && tlist[b] > key) { tlist[b+1] = tlist[b]; b--; }
            tlist[b+1] = key;
        }
        unsigned r = R;
        if (r > n2) r = n2;
        if (r < 1u) r = 1u;
        scut = (n2 > 0u) ? tlist[r - 1] : 0u;
    }
    __syncthreads();
    unsigned cut = scut;
    // ---- write the selected set (order-free; downstream sums order-free) ----
    for (unsigned i = t; i < M; i += 256) {
        unsigned u  = ok ? cval[i] : __float_as_uint(mrow[i]);
        unsigned id = ok ? cidx[i] : i;
        if (u > T || (u == T && id <= cut)) {
            unsigned p = atomicAdd(&ns, 1u);
            if (p < K_SEL) {
                const float* gm = means + ((size_t)row * HW_N + id) * 3;
                float sx = gm[0], sy = gm[1], sz = gm[2];
                float sa = fmaf(sx, sx, fmaf(sy, sy, sz * sz));
                float w  = (u > HALF_BITS) ? sa : -1.0f;
                sampbuf[(size_t)row * K_SEL + p] = make_float4(sx, sy, sz, w);
            }
        }
    }
}

// ---------------------------------------------------------------------------
// Kernel 3: NN partial mins. 1024 blocks = (row, mesh-slice of 98 points).
// 128 threads; each lane holds 8 samples in regs -> one broadcast LDS read
// serves 512 pairs. No atomics, no fences.
// ---------------------------------------------------------------------------
__global__ void __launch_bounds__(128) dist_kernel(
    const float4* __restrict__ meshP, const float4* __restrict__ sampbuf,
    float* __restrict__ minpart)
{
    __shared__ float4 mq[SLICE];
    int blk = blockIdx.x;
    int r = blk >> 4, sl = blk & 15;
    int t = threadIdx.x;

    if (t < SLICE) mq[t] = meshP[r * NMESH_PAD + sl * SLICE + t];

    const float4* sb = sampbuf + (size_t)r * K_SEL;
    float sx[8], sy[8], sz[8], mn[8];
#pragma unroll
    for (int k = 0; k < 8; k++) {
        float4 s = sb[t + 128*k];
        sx[k] = s.x; sy[k] = s.y; sz[k] = s.z;
        mn[k] = 3.4e38f;
    }
    __syncthreads();

#pragma unroll 2
    for (int i = 0; i < SLICE; i++) {
        float4 a = mq[i];
#pragma unroll
        for (int k = 0; k < 8; k++)
            mn[k] = fminf(mn[k], fmaf(sx[k], a.x, fmaf(sy[k], a.y, fmaf(sz[k], a.z, a.w))));
    }

    float* mp = minpart + ((size_t)r * NSLICE + sl) * K_SEL;
#pragma unroll
    for (int k = 0; k < 8; k++) mp[t + 128*k] = mn[k];
}

// ---------------------------------------------------------------------------
// Kernel 4: per-sample min over 16 slices + per-row fixed-point sum +
// last-of-64 ticket finalize. Integer adds -> order-invariant -> deterministic.
// ---------------------------------------------------------------------------
__global__ void __launch_bounds__(256) reduce_kernel(
    const float* __restrict__ minpart, const float4* __restrict__ sampbuf,
    unsigned* __restrict__ ctr, float* __restrict__ out)
{
    __shared__ long long rs[256];
    __shared__ unsigned rc[256];
    int row = blockIdx.x;
    int t = threadIdx.x;

    long long acc = 0; unsigned c = 0;
#pragma unroll
    for (int k = 0; k < 4; k++) {
        int j = k * 256 + t;
        const float* mp = minpart + (size_t)row * NSLICE * K_SEL + j;
        float m = mp[0];
#pragma unroll
        for (int s = 1; s < NSLICE; s++) m = fminf(m, mp[s * (int)K_SEL]);
        float4 sp = sampbuf[(size_t)row * K_SEL + j];
        if (sp.w >= 0.0f) {
            float d2 = fmaxf(m + sp.w, 0.0f);
            acc += (long long)((double)d2 * FIX_SCALE);
            c += 1u;
        }
    }
    rs[t] = acc; rc[t] = c;
    __syncthreads();
    for (int off = 128; off > 0; off >>= 1) {
        if (t < off) { rs[t] += rs[t+off]; rc[t] += rc[t+off]; }
        __syncthreads();
    }
    if (t == 0) {
        atomicAdd((u64*)ctr, (u64)rs[0]);
        atomicAdd(&ctr[2], rc[0]);
        __threadfence();
        unsigned tk = atomicAdd(&ctr[3], 1u);
        if (tk == (unsigned)(NROW - 1)) {
            u64 sbits = atomicAdd((u64*)ctr, 0ull);
            unsigned cc = atomicAdd(&ctr[2], 0u);
            double sum = (double)(long long)sbits / FIX_SCALE;
            out[0] = (float)(sum / (double)(cc ? cc : 1u));
        }
    }
}

extern "C" void kernel_launch(void* const* d_in, const int* in_sizes, int n_in,
                              void* d_out, int out_size, void* d_ws, size_t ws_size,
                              hipStream_t stream) {
    const float* hp    = (const float*)d_in[0];
    const float* means = (const float*)d_in[1];
    const float* mask  = (const float*)d_in[2];
    const int*   hv    = (const int*)  d_in[3];
    const float* vtl   = (const float*)d_in[4];
    const float* vtr   = (const float*)d_in[5];
    const float* sdl   = (const float*)d_in[6];
    const float* sdr   = (const float*)d_in[7];
    const float* pdl   = (const float*)d_in[8];
    const float* pdr   = (const float*)d_in[9];
    float* out = (float*)d_out;

    char* ws = (char*)d_ws;
    u64*      cand    = (u64*)(ws + OFF_CAND);
    unsigned* ccnt    = (unsigned*)(ws + OFF_CCNT);
    unsigned* ctr     = (unsigned*)(ws + OFF_CTR);
    float4*   meshP   = (float4*)(ws + OFF_MESH);
    float4*   sampbuf = (float4*)(ws + OFF_SAMP);
    float*    minpart = (float*)(ws + OFF_MINP);

    combo_kernel<<<1024 + 128, 256, 0, stream>>>(mask, hv, cand, ccnt,
                                                 hp, vtl, vtr, sdl, sdr, pdl, pdr, meshP);
    sel_fin_kernel<<<NROW, 256, 0, stream>>>(mask, means, hv, cand, ccnt, sampbuf, ctr);
    dist_kernel<<<NROW * NSLICE, 128, 0, stream>>>(meshP, sampbuf, minpart);
    reduce_kernel<<<NROW, 256, 0, stream>>>(minpart, sampbuf, ctr, out);
}